// Round 15
// baseline (106.183 us; speedup 1.0000x reference)
//
#include <hip/hip_runtime.h>
#include <math.h>

namespace {

constexpr int B_ = 8, L_ = 4096, C_ = 128, K_ = 7;
constexpr int LP = L_ - K_ + 1;        // 4090
constexpr int CK = C_ * K_;            // 896
constexpr size_t NX = (size_t)B_ * L_ * C_;   // 4194304 elements

typedef __attribute__((ext_vector_type(8))) _Float16 half8v;   // 4 VGPR MFMA frag
typedef __attribute__((ext_vector_type(4))) float f32x4;

// tanh(v) = 1 - 2/(e^{2v}+1) — both signs, no abs/sign dance. rcp err ~1e-5.
__device__ __forceinline__ float fast_tanh(float v) {
    float e = __expf(2.0f * v);
    return fmaf(-2.0f, __builtin_amdgcn_rcpf(e + 1.0f), 1.0f);
}

// x fp32 -> fp16 (RNE), 8 elems/thread. Runs once, ~4us; d_ws poison fill is
// already in the timed window whether we use ws or not (R12 evidence), so
// this offload is effectively free and deletes all in-loop cvt VALU.
__global__ void convert_x(const float* __restrict__ x, _Float16* __restrict__ xh) {
    size_t i = (size_t)(blockIdx.x * 256 + threadIdx.x) * 8;
    if (i >= NX) return;
    const float4 f0 = *reinterpret_cast<const float4*>(&x[i]);
    const float4 f1 = *reinterpret_cast<const float4*>(&x[i + 4]);
    half8v h;
    h[0] = (_Float16)f0.x; h[1] = (_Float16)f0.y;
    h[2] = (_Float16)f0.z; h[3] = (_Float16)f0.w;
    h[4] = (_Float16)f1.x; h[5] = (_Float16)f1.y;
    h[6] = (_Float16)f1.z; h[7] = (_Float16)f1.w;
    *reinterpret_cast<half8v*>(&xh[i]) = h;
}

// Main kernel: 256 l-rows x 16 d per block; 4 waves x 64 rows each.
// m-tiles processed in PAIRS sharing each B fragment read (LDS reads halved
// vs R12: 56 ds_read_b128/wave) with 4 independent MFMA chains per nt.
// PRECONV: A-fragments load directly from pre-converted fp16 x (no cvt VALU,
// no float staging) -> live set ~96 VGPR -> 5 blocks/CU (LDS allows 5).
template <bool PRECONV>
__global__ __launch_bounds__(256, 2) void sidechain_fused(
        const float* __restrict__ x, const _Float16* __restrict__ xh,
        const float* __restrict__ W, float* __restrict__ out) {
    __shared__ _Float16 Bs[7 * 16 * C_];   // [k][d_local][cin], XOR-swizzled 16B granules

    const int tid = threadIdx.x;
    const int b  = blockIdx.x >> 4;
    const int l0 = (blockIdx.x & 15) * 256;
    const int d0 = blockIdx.y * 16;
    const float*    xb  = x  + (size_t)b * (L_ * C_);
    const _Float16* xhb = xh + (size_t)b * (L_ * C_);

    // ---- stage + convert W tile straight from fp32 global (RNE to fp16)
    {
        const int dl = tid >> 4;       // 0..15: d row
        const int g  = tid & 15;       // cin granule (8 cins)
        const int gp = g ^ dl;         // swizzled granule slot
        const float* wp = W + (size_t)(d0 + dl) * CK + g * 56;  // 8 cins x 7 k, contiguous
        float wbuf[56];
#pragma unroll
        for (int i = 0; i < 14; ++i)
            *reinterpret_cast<float4*>(&wbuf[i * 4]) =
                *reinterpret_cast<const float4*>(&wp[i * 4]);
#pragma unroll
        for (int k = 0; k < 7; ++k) {
            half8v h;
#pragma unroll
            for (int c = 0; c < 8; ++c) h[c] = (_Float16)wbuf[c * 7 + k];
            *reinterpret_cast<half8v*>(&Bs[(k * 16 + dl) * C_ + gp * 8]) = h;
        }
    }
    __syncthreads();

    const int wv   = tid >> 6;
    const int lane = tid & 63;
    const int rA   = lane & 15;    // A row / B col(d) / D col
    const int kg   = lane >> 4;    // 0..3
    const int dcol = d0 + rA;
    const int rowA0 = l0 + 6 + wv * 64 + rA;   // + mt*16
    const int rowX0 = l0 + wv * 64 + kg * 4;   // + mt*16 + r2

#pragma unroll 1
    for (int half = 0; half < 2; ++half) {     // pair of m-tiles per iteration
        half8v A[2][4];
        float  xv[2][10];
#pragma unroll
        for (int m = 0; m < 2; ++m) {
            int mt = half * 2 + m;
            int r = rowA0 + mt * 16;
            if (r > L_ - 1) r = L_ - 1;        // clamped rows feed masked-out outputs only
            if (PRECONV) {
                const _Float16* xr = xhb + (size_t)r * C_;
#pragma unroll
                for (int ks = 0; ks < 4; ++ks)
                    A[m][ks] = *reinterpret_cast<const half8v*>(xr + ks * 32 + kg * 8);
            } else {
                const float* xr = xb + (size_t)r * C_;
#pragma unroll
                for (int ks = 0; ks < 4; ++ks) {
                    const float* p = xr + ks * 32 + kg * 8;
                    const float4 f0 = *reinterpret_cast<const float4*>(p);
                    const float4 f1 = *reinterpret_cast<const float4*>(p + 4);
                    half8v h;
                    h[0] = (_Float16)f0.x; h[1] = (_Float16)f0.y;
                    h[2] = (_Float16)f0.z; h[3] = (_Float16)f0.w;
                    h[4] = (_Float16)f1.x; h[5] = (_Float16)f1.y;
                    h[6] = (_Float16)f1.z; h[7] = (_Float16)f1.w;
                    A[m][ks] = h;
                }
            }
            int base = rowX0 + mt * 16;
#pragma unroll
            for (int r2 = 0; r2 < 10; ++r2) {
                int row = base + r2;
                if (row > L_ - 1) row = L_ - 1;    // OOB only for masked-out outputs
                xv[m][r2] = xb[(size_t)row * C_ + dcol];
            }
        }

        f32x4 oacc[2];
        oacc[0] = (f32x4)(0.0f); oacc[1] = (f32x4)(0.0f);

#pragma unroll
        for (int nt = 0; nt < 7; ++nt) {       // n-tile == tap k
            f32x4 a0[2], a1[2];                // 4 independent MFMA chains
            a0[0] = (f32x4)(0.0f); a0[1] = (f32x4)(0.0f);
            a1[0] = (f32x4)(0.0f); a1[1] = (f32x4)(0.0f);
            const _Float16* brow = &Bs[(nt * 16 + rA) * C_];
#pragma unroll
            for (int kp = 0; kp < 4; kp += 2) {
                int g0 = (kp * 4 + kg) ^ rA;
                int g1 = ((kp + 1) * 4 + kg) ^ rA;
                const half8v B0 = *reinterpret_cast<const half8v*>(brow + g0 * 8);
                const half8v B1 = *reinterpret_cast<const half8v*>(brow + g1 * 8);
#pragma unroll
                for (int m = 0; m < 2; ++m) {
                    a0[m] = __builtin_amdgcn_mfma_f32_16x16x32_f16(A[m][kp],     B0, a0[m], 0, 0, 0);
                    a1[m] = __builtin_amdgcn_mfma_f32_16x16x32_f16(A[m][kp + 1], B1, a1[m], 0, 0, 0);
                }
            }
#pragma unroll
            for (int m = 0; m < 2; ++m)
#pragma unroll
                for (int r = 0; r < 4; ++r)
                    oacc[m][r] = fmaf(xv[m][r + nt], fast_tanh(a0[m][r] + a1[m][r]), oacc[m][r]);
        }

#pragma unroll
        for (int m = 0; m < 2; ++m) {
            int mt = half * 2 + m;
#pragma unroll
            for (int r = 0; r < 4; ++r) {
                int l = rowX0 + mt * 16 + r;
                if (l < LP) out[((size_t)b * LP + l) * C_ + dcol] = oacc[m][r];
            }
        }
    }
}

} // namespace

extern "C" void kernel_launch(void* const* d_in, const int* in_sizes, int n_in,
                              void* d_out, int out_size, void* d_ws, size_t ws_size,
                              hipStream_t stream) {
    const float* x = (const float*)d_in[0];
    const float* w = (const float*)d_in[1];
    float* out     = (float*)d_out;
    (void)in_sizes; (void)n_in; (void)out_size;

    dim3 grid(B_ * 16, C_ / 16);
    const size_t need = NX * sizeof(_Float16);   // 8 MB
    if (ws_size >= need) {
        _Float16* xh = (_Float16*)d_ws;
        convert_x<<<dim3((int)(NX / 8 / 256)), dim3(256), 0, stream>>>(x, xh);
        sidechain_fused<true><<<grid, dim3(256), 0, stream>>>(x, xh, w, out);
    } else {
        sidechain_fused<false><<<grid, dim3(256), 0, stream>>>(x, nullptr, w, out);
    }
}